// Round 1
// baseline (203.213 us; speedup 1.0000x reference)
//
#include <hip/hip_runtime.h>
#include <hip/hip_bf16.h>
#include <stdint.h>

// AttentionBlock: GN(8) -> qkv 1x1 -> attention(1024 tok, d=256) -> proj -> +x
// b=32, c=256, h=w=32 (hw=1024). All fp32 in/out; bf16 MFMA internally.

typedef __bf16 bf16_t;
typedef __bf16 bf16x8 __attribute__((ext_vector_type(8)));
typedef float f32x4 __attribute__((ext_vector_type(4)));

#define MFMA(a, b, c) __builtin_amdgcn_mfma_f32_16x16x32_bf16((a), (b), (c), 0, 0, 0)

// ---------------- K0: fp32 -> bf16 cast (weights) ----------------
__global__ void cast_bf16(const float* __restrict__ s, bf16_t* __restrict__ d, int n) {
    for (int i = blockIdx.x * blockDim.x + threadIdx.x; i < n; i += gridDim.x * blockDim.x)
        d[i] = (bf16_t)s[i];
}

// ---------------- K1: GroupNorm + transpose to (b, pixel, c) bf16 ----------------
// one block per (b, g): 32 channels x 1024 pixels
__global__ __launch_bounds__(256) void gn_kernel(const float* __restrict__ x,
                                                 const float* __restrict__ gamma,
                                                 const float* __restrict__ beta,
                                                 bf16_t* __restrict__ xn) {
    int bg = blockIdx.x;
    int b = bg >> 3, g = bg & 7;
    const float* base = x + (size_t)(b * 256 + g * 32) * 1024;
    int tid = threadIdx.x;

    float s = 0.f, ss = 0.f;
    for (int i = tid; i < 32768; i += 256) { float v = base[i]; s += v; ss += v * v; }
    for (int off = 32; off; off >>= 1) { s += __shfl_down(s, off); ss += __shfl_down(ss, off); }
    __shared__ float rA[4], rB[4];
    __shared__ float sM, sR;
    int w = tid >> 6, lane = tid & 63;
    if (lane == 0) { rA[w] = s; rB[w] = ss; }
    __syncthreads();
    if (tid == 0) {
        float S = rA[0] + rA[1] + rA[2] + rA[3];
        float SS = rB[0] + rB[1] + rB[2] + rB[3];
        float mean = S * (1.0f / 32768.0f);
        float var = SS * (1.0f / 32768.0f) - mean * mean;
        sM = mean; sR = rsqrtf(var + 1e-5f);
    }
    __syncthreads();
    float mean = sM, rstd = sR;

    __shared__ bf16_t tile[64][34];  // 64 px x 32 ch, padded
    for (int p0 = 0; p0 < 1024; p0 += 64) {
        __syncthreads();
        #pragma unroll
        for (int i = 0; i < 8; i++) {
            int idx = i * 256 + tid;
            int c = idx >> 6, p = idx & 63;
            float v = base[c * 1024 + p0 + p];
            int cg = g * 32 + c;
            float vn = (v - mean) * rstd * gamma[cg] + beta[cg];
            tile[p][c] = (bf16_t)vn;
        }
        __syncthreads();
        #pragma unroll
        for (int i = 0; i < 8; i++) {
            int idx = i * 256 + tid;
            int p = idx >> 5, c = idx & 31;
            xn[(size_t)(b * 1024 + p0 + p) * 256 + g * 32 + c] = tile[p][c];
        }
    }
}

// ---------------- K2: QKV GEMM  C[m,d] = sum_k xn[m,k]*W[d,k] + bias ----------------
// m = b*1024+pixel (32768), d in [0,768). Q,K -> (b,n,256) row-major; V -> (b,256,n) transposed.
// 64x64 tile, 4 waves, K=256 staged whole. Rows are 512B; XOR-swizzled LDS.
__global__ __launch_bounds__(256) void gemm_qkv(const bf16_t* __restrict__ xn,
                                                const bf16_t* __restrict__ wq,
                                                const float* __restrict__ qkv_b,
                                                bf16_t* __restrict__ qb,
                                                bf16_t* __restrict__ kb,
                                                bf16_t* __restrict__ vt) {
    __shared__ char smem[65536];
    char* As = smem;
    char* Bs = smem + 32768;
    int tid = threadIdx.x;
    int m0 = blockIdx.x * 64, n0 = blockIdx.y * 64;
    const char* asrc = (const char*)xn + (size_t)m0 * 512;
    const char* bsrc = (const char*)wq + (size_t)n0 * 512;

    float4 ta[8], tb[8];
    #pragma unroll
    for (int i = 0; i < 8; i++) {
        int t = i * 256 + tid, row = t >> 5, sl = t & 31;
        ta[i] = *(const float4*)(asrc + row * 512 + sl * 16);
        tb[i] = *(const float4*)(bsrc + row * 512 + sl * 16);
    }
    #pragma unroll
    for (int i = 0; i < 8; i++) {
        int t = i * 256 + tid, row = t >> 5, sl = t & 31;
        int off = (sl * 16) ^ ((row & 7) << 4);
        *(float4*)(As + row * 512 + off) = ta[i];
        *(float4*)(Bs + row * 512 + off) = tb[i];
    }
    __syncthreads();

    int wv = tid >> 6, lane = tid & 63, lrow = lane & 15, lgr = lane >> 4;
    int arow = wv * 16 + lrow;
    f32x4 acc[4] = {};
    #pragma unroll
    for (int s = 0; s < 8; s++) {
        int koff = s * 64 + lgr * 16;
        bf16x8 af = *(const bf16x8*)(As + arow * 512 + (koff ^ ((arow & 7) << 4)));
        #pragma unroll
        for (int ct = 0; ct < 4; ct++) {
            int brow = ct * 16 + lrow;
            bf16x8 bfr = *(const bf16x8*)(Bs + brow * 512 + (koff ^ ((brow & 7) << 4)));
            acc[ct] = MFMA(af, bfr, acc[ct]);
        }
    }

    if (n0 < 512) {  // Q / K: direct coalesced-ish writes
        #pragma unroll
        for (int ct = 0; ct < 4; ct++) {
            int d = n0 + ct * 16 + lrow;
            float bias = qkv_b[d];
            #pragma unroll
            for (int r = 0; r < 4; r++) {
                int m = m0 + wv * 16 + lgr * 4 + r;
                float val = acc[ct][r] + bias;
                if (d < 256) qb[(size_t)m * 256 + d] = (bf16_t)val;
                else kb[(size_t)m * 256 + (d - 256)] = (bf16_t)val;
            }
        }
    } else {  // V: transpose through LDS, write (b, d, n)
        __syncthreads();
        bf16_t* tt = (bf16_t*)smem;  // 64 x 66 padded
        #pragma unroll
        for (int ct = 0; ct < 4; ct++) {
            int d = n0 + ct * 16 + lrow;
            float bias = qkv_b[d];
            #pragma unroll
            for (int r = 0; r < 4; r++)
                tt[(ct * 16 + lrow) * 66 + wv * 16 + lgr * 4 + r] = (bf16_t)(acc[ct][r] + bias);
        }
        __syncthreads();
        int bb = m0 >> 10, nbase = m0 & 1023;
        #pragma unroll
        for (int i = 0; i < 16; i++) {
            int e = i * 256 + tid;
            int d_l = e >> 6, m_l = e & 63;
            vt[(size_t)bb * 262144 + (size_t)(n0 - 512 + d_l) * 1024 + nbase + m_l] =
                tt[d_l * 66 + m_l];
        }
    }
}

// ---------------- K3: fused attention ----------------
// block = (qt, b): 64 q-rows, 4 waves x 16 rows. KV chunks of 32. Online softmax (defer-max).
__global__ __launch_bounds__(256) void attn_kernel(const bf16_t* __restrict__ qb,
                                                   const bf16_t* __restrict__ kb,
                                                   const bf16_t* __restrict__ vt,
                                                   bf16_t* __restrict__ ao) {
    __shared__ char smem[36864];
    char* Ks = smem;           // 32 rows x 512B (swizzled)
    char* Vs = smem + 16384;   // 256 rows x 64B (swizzled) — V^T chunk
    char* Ps = smem + 32768;   // 4 waves x 16 rows x 64B (swizzled)
    int tid = threadIdx.x;
    int qt = blockIdx.x, b = blockIdx.y;
    int wv = tid >> 6, lane = tid & 63, lrow = lane & 15, lgr = lane >> 4;
    char* Pw = Ps + wv * 1024;

    int qrow = qt * 64 + wv * 16 + lrow;
    const char* qsrc = (const char*)qb + (size_t)(b * 1024 + qrow) * 512;
    bf16x8 qf[8];
    #pragma unroll
    for (int s = 0; s < 8; s++) qf[s] = *(const bf16x8*)(qsrc + s * 64 + lgr * 16);

    f32x4 o[16] = {};
    float mprev[4] = {-1e30f, -1e30f, -1e30f, -1e30f};
    float lsum[4] = {0.f, 0.f, 0.f, 0.f};
    const char* kbase = (const char*)kb + (size_t)b * 524288;
    const char* vbase = (const char*)vt + (size_t)b * 524288;

    for (int ch = 0; ch < 32; ch++) {
        int j0 = ch * 32;
        __syncthreads();
        float4 tk[4], tv[4];
        #pragma unroll
        for (int i = 0; i < 4; i++) {
            int t = i * 256 + tid;
            int krow = t >> 5, ksl = t & 31;
            tk[i] = *(const float4*)(kbase + (size_t)(j0 + krow) * 512 + ksl * 16);
            int vrow = t >> 2, vsl = t & 3;
            tv[i] = *(const float4*)(vbase + (size_t)vrow * 2048 + j0 * 2 + vsl * 16);
        }
        #pragma unroll
        for (int i = 0; i < 4; i++) {
            int t = i * 256 + tid;
            int krow = t >> 5, ksl = t & 31;
            *(float4*)(Ks + krow * 512 + ((ksl * 16) ^ ((krow & 7) << 4))) = tk[i];
            int vrow = t >> 2, vsl = t & 3;
            *(float4*)(Vs + vrow * 64 + ((vsl * 16) ^ ((vrow & 3) << 4))) = tv[i];
        }
        __syncthreads();

        // S = Q K^T for this 64x32 chunk (2 col-tiles per wave)
        f32x4 s0 = {0.f, 0.f, 0.f, 0.f}, s1 = {0.f, 0.f, 0.f, 0.f};
        #pragma unroll
        for (int s = 0; s < 8; s++) {
            int koff = s * 64 + lgr * 16;
            bf16x8 b0 = *(const bf16x8*)(Ks + lrow * 512 + (koff ^ ((lrow & 7) << 4)));
            bf16x8 b1 = *(const bf16x8*)(Ks + (16 + lrow) * 512 + (koff ^ ((lrow & 7) << 4)));
            s0 = MFMA(qf[s], b0, s0);
            s1 = MFMA(qf[s], b1, s1);
        }

        // online softmax, defer-max (THR=8)
        float alpha[4];
        bool need = false;
        #pragma unroll
        for (int r = 0; r < 4; r++) {
            float sv0 = s0[r] * 0.0625f, sv1 = s1[r] * 0.0625f;
            float cm = fmaxf(sv0, sv1);
            cm = fmaxf(cm, __shfl_xor(cm, 1));
            cm = fmaxf(cm, __shfl_xor(cm, 2));
            cm = fmaxf(cm, __shfl_xor(cm, 4));
            cm = fmaxf(cm, __shfl_xor(cm, 8));
            float mo = mprev[r];
            float mn = (cm <= mo + 8.0f) ? mo : cm;
            float a_ = __expf(mo - mn);
            alpha[r] = a_;
            need = need || (mn != mo);
            mprev[r] = mn;
            float p0 = __expf(sv0 - mn), p1 = __expf(sv1 - mn);
            float rs = p0 + p1;
            rs += __shfl_xor(rs, 1);
            rs += __shfl_xor(rs, 2);
            rs += __shfl_xor(rs, 4);
            rs += __shfl_xor(rs, 8);
            lsum[r] = lsum[r] * a_ + rs;
            int i_ = lgr * 4 + r;
            *(bf16_t*)(Pw + i_ * 64 + ((lrow * 2) ^ ((i_ & 3) << 4))) = (bf16_t)p0;
            *(bf16_t*)(Pw + i_ * 64 + ((32 + lrow * 2) ^ ((i_ & 3) << 4))) = (bf16_t)p1;
        }
        if (need) {
            #pragma unroll
            for (int dt = 0; dt < 16; dt++) {
                #pragma unroll
                for (int r = 0; r < 4; r++) o[dt][r] *= alpha[r];
            }
        }

        // O += P V   (A-frag from wave-local P, B-frag from V^T rows)
        bf16x8 pa = *(const bf16x8*)(Pw + lrow * 64 + ((lgr * 16) ^ ((lrow & 3) << 4)));
        #pragma unroll
        for (int dt = 0; dt < 16; dt++) {
            int vrow = dt * 16 + lrow;
            bf16x8 vb = *(const bf16x8*)(Vs + vrow * 64 + ((lgr * 16) ^ ((vrow & 3) << 4)));
            o[dt] = MFMA(pa, vb, o[dt]);
        }
    }

    #pragma unroll
    for (int r = 0; r < 4; r++) {
        float inv = 1.0f / lsum[r];
        int rg = qt * 64 + wv * 16 + lgr * 4 + r;
        bf16_t* dst = ao + (size_t)(b * 1024 + rg) * 256;
        #pragma unroll
        for (int dt = 0; dt < 16; dt++) dst[dt * 16 + lrow] = (bf16_t)(o[dt][r] * inv);
    }
}

// ---------------- K4: out-proj GEMM + bias + residual ----------------
// D[c,n] = sum_k W[c,k] * AO[n,k];  out[b,c,n] = D + out_b[c] + x[b,c,n]
__global__ __launch_bounds__(256) void gemm_out(const bf16_t* __restrict__ wo,
                                                const bf16_t* __restrict__ ao,
                                                const float* __restrict__ out_b,
                                                const float* __restrict__ x,
                                                float* __restrict__ out) {
    __shared__ char smem[65536];
    char* As = smem;
    char* Bs = smem + 32768;
    int tid = threadIdx.x;
    int c0 = blockIdx.x * 64, n0 = blockIdx.y * 64, b = blockIdx.z;
    const char* asrc = (const char*)wo + (size_t)c0 * 512;
    const char* bsrc = (const char*)ao + ((size_t)b * 1024 + n0) * 512;

    float4 ta[8], tb[8];
    #pragma unroll
    for (int i = 0; i < 8; i++) {
        int t = i * 256 + tid, row = t >> 5, sl = t & 31;
        ta[i] = *(const float4*)(asrc + row * 512 + sl * 16);
        tb[i] = *(const float4*)(bsrc + row * 512 + sl * 16);
    }
    #pragma unroll
    for (int i = 0; i < 8; i++) {
        int t = i * 256 + tid, row = t >> 5, sl = t & 31;
        int off = (sl * 16) ^ ((row & 7) << 4);
        *(float4*)(As + row * 512 + off) = ta[i];
        *(float4*)(Bs + row * 512 + off) = tb[i];
    }
    __syncthreads();

    int wv = tid >> 6, lane = tid & 63, lrow = lane & 15, lgr = lane >> 4;
    int arow = wv * 16 + lrow;
    f32x4 acc[4] = {};
    #pragma unroll
    for (int s = 0; s < 8; s++) {
        int koff = s * 64 + lgr * 16;
        bf16x8 af = *(const bf16x8*)(As + arow * 512 + (koff ^ ((arow & 7) << 4)));
        #pragma unroll
        for (int ct = 0; ct < 4; ct++) {
            int brow = ct * 16 + lrow;
            bf16x8 bfr = *(const bf16x8*)(Bs + brow * 512 + (koff ^ ((brow & 7) << 4)));
            acc[ct] = MFMA(af, bfr, acc[ct]);
        }
    }

    #pragma unroll
    for (int ct = 0; ct < 4; ct++) {
        int n = n0 + ct * 16 + lrow;
        #pragma unroll
        for (int r = 0; r < 4; r++) {
            int c = c0 + wv * 16 + lgr * 4 + r;
            size_t idx = ((size_t)b * 256 + c) * 1024 + n;
            out[idx] = acc[ct][r] + out_b[c] + x[idx];
        }
    }
}

// ---------------- launcher ----------------
extern "C" void kernel_launch(void* const* d_in, const int* in_sizes, int n_in,
                              void* d_out, int out_size, void* d_ws, size_t ws_size,
                              hipStream_t stream) {
    (void)in_sizes; (void)n_in; (void)out_size; (void)ws_size;
    const float* x      = (const float*)d_in[0];
    const float* gamma  = (const float*)d_in[1];
    const float* beta   = (const float*)d_in[2];
    const float* qkv_w  = (const float*)d_in[3];
    const float* qkv_b  = (const float*)d_in[4];
    const float* out_w  = (const float*)d_in[5];
    const float* out_b  = (const float*)d_in[6];
    float* out = (float*)d_out;

    char* ws = (char*)d_ws;
    const size_t MB16 = 16777216;
    bf16_t* xn  = (bf16_t*)(ws);             // (b, n, 256) bf16
    bf16_t* qb  = (bf16_t*)(ws + 1 * MB16);  // (b, n, 256)
    bf16_t* kb  = (bf16_t*)(ws + 2 * MB16);  // (b, n, 256)
    bf16_t* vt  = (bf16_t*)(ws + 3 * MB16);  // (b, 256, n)  V transposed
    bf16_t* ao  = (bf16_t*)(ws + 4 * MB16);  // (b, n, 256)
    bf16_t* wqb = (bf16_t*)(ws + 5 * MB16);            // 768x256 bf16
    bf16_t* wob = (bf16_t*)(ws + 5 * MB16 + 393216);   // 256x256 bf16

    cast_bf16<<<192, 256, 0, stream>>>(qkv_w, wqb, 196608);
    cast_bf16<<<64, 256, 0, stream>>>(out_w, wob, 65536);
    gn_kernel<<<256, 256, 0, stream>>>(x, gamma, beta, xn);
    gemm_qkv<<<dim3(512, 12), 256, 0, stream>>>(xn, wqb, qkv_b, qb, kb, vt);
    attn_kernel<<<dim3(16, 32), 256, 0, stream>>>(qb, kb, vt, ao);
    gemm_out<<<dim3(4, 16, 32), 256, 0, stream>>>(wob, ao, out_b, x, out);
}

// Round 2
// 144.045 us; speedup vs baseline: 1.4108x; 1.4108x over previous
//
#include <hip/hip_runtime.h>
#include <hip/hip_bf16.h>
#include <stdint.h>

// AttentionBlock: GN(8) -> qkv 1x1 -> attention(1024 tok, d=256) -> proj -> +x
// b=32, c=256, h=w=32 (hw=1024). fp32 in/out; bf16 MFMA internally.

typedef __bf16 bf16_t;
typedef __bf16 bf16x4 __attribute__((ext_vector_type(4)));
typedef __bf16 bf16x8 __attribute__((ext_vector_type(8)));
typedef float f32x4 __attribute__((ext_vector_type(4)));
typedef float f32x16 __attribute__((ext_vector_type(16)));
typedef _Float16 f16x4 __attribute__((ext_vector_type(4)));

#define MFMA16(a, b, c) __builtin_amdgcn_mfma_f32_16x16x32_bf16((a), (b), (c), 0, 0, 0)
#define MFMA32(a, b, c) __builtin_amdgcn_mfma_f32_32x32x16_bf16((a), (b), (c), 0, 0, 0)
#define GLL16(g, l)                                                                     \
    __builtin_amdgcn_global_load_lds((const __attribute__((address_space(1))) void*)(g), \
                                     (__attribute__((address_space(3))) void*)(l), 16, 0, 0)

// ---------------- K0: fp32 -> bf16 cast (weights) ----------------
__global__ void cast_bf16(const float* __restrict__ s, bf16_t* __restrict__ d, int n) {
    for (int i = blockIdx.x * blockDim.x + threadIdx.x; i < n; i += gridDim.x * blockDim.x)
        d[i] = (bf16_t)s[i];
}

// ---------------- K1: GroupNorm + transpose to (b, pixel, c) bf16 ----------------
// one block per (b, g): 32 ch x 1024 px. Single HBM read: stash x as fp16 in LDS.
__global__ __launch_bounds__(256) void gn_kernel(const float* __restrict__ x,
                                                 const float* __restrict__ gamma,
                                                 const float* __restrict__ beta,
                                                 bf16_t* __restrict__ xn) {
    extern __shared__ char gsm[];               // 65536 (fp16 stash) + 64 (reduce)
    float* red = (float*)(gsm + 65536);
    int bg = blockIdx.x, b = bg >> 3, g = bg & 7;
    const float* base = x + (size_t)(b * 256 + g * 32) * 1024;
    int tid = threadIdx.x;

    float s = 0.f, ss = 0.f;
    #pragma unroll 4
    for (int c = 0; c < 32; c++) {
        float4 v = *(const float4*)(base + c * 1024 + tid * 4);
        s += v.x + v.y + v.z + v.w;
        ss += v.x * v.x + v.y * v.y + v.z * v.z + v.w * v.w;
        f16x4 h = {(_Float16)v.x, (_Float16)v.y, (_Float16)v.z, (_Float16)v.w};
        *(f16x4*)(gsm + c * 2048 + ((tid * 8) ^ ((c & 7) << 4))) = h;
    }
    for (int off = 32; off; off >>= 1) { s += __shfl_down(s, off); ss += __shfl_down(ss, off); }
    if ((tid & 63) == 0) { red[tid >> 6] = s; red[4 + (tid >> 6)] = ss; }
    __syncthreads();
    float S = red[0] + red[1] + red[2] + red[3];
    float SS = red[4] + red[5] + red[6] + red[7];
    float mean = S * (1.0f / 32768.0f);
    float var = SS * (1.0f / 32768.0f) - mean * mean;
    float rstd = rsqrtf(var + 1e-5f);

    int c = tid & 31;
    float gam = gamma[g * 32 + c] * rstd;
    float bet = beta[g * 32 + c] - mean * gam;
    bf16_t* dst = xn + (size_t)(b * 1024) * 256 + g * 32 + c;
    #pragma unroll 4
    for (int it = 0; it < 128; it++) {
        int p = it * 8 + (tid >> 5);
        _Float16 hv = *(_Float16*)(gsm + c * 2048 + ((p * 2) ^ ((c & 7) << 4)));
        dst[(size_t)p * 256] = (bf16_t)((float)hv * gam + bet);
    }
}

// ---------------- K2: QKV GEMM  C[m,d] = sum_k xn[m,k]*W[d,k] + bias ----------------
__global__ __launch_bounds__(256) void gemm_qkv(const bf16_t* __restrict__ xn,
                                                const bf16_t* __restrict__ wq,
                                                const float* __restrict__ qkv_b,
                                                bf16_t* __restrict__ qb,
                                                bf16_t* __restrict__ kb,
                                                bf16_t* __restrict__ vt) {
    __shared__ char smem[65536];
    char* As = smem;
    char* Bs = smem + 32768;
    int tid = threadIdx.x;
    int m0 = blockIdx.x * 64, n0 = blockIdx.y * 64;
    const char* asrc = (const char*)xn + (size_t)m0 * 512;
    const char* bsrc = (const char*)wq + (size_t)n0 * 512;

    float4 ta[8], tb[8];
    #pragma unroll
    for (int i = 0; i < 8; i++) {
        int t = i * 256 + tid, row = t >> 5, sl = t & 31;
        ta[i] = *(const float4*)(asrc + row * 512 + sl * 16);
        tb[i] = *(const float4*)(bsrc + row * 512 + sl * 16);
    }
    #pragma unroll
    for (int i = 0; i < 8; i++) {
        int t = i * 256 + tid, row = t >> 5, sl = t & 31;
        int off = (sl * 16) ^ ((row & 7) << 4);
        *(float4*)(As + row * 512 + off) = ta[i];
        *(float4*)(Bs + row * 512 + off) = tb[i];
    }
    __syncthreads();

    int wv = tid >> 6, lane = tid & 63, lrow = lane & 15, lgr = lane >> 4;
    int arow = wv * 16 + lrow;
    f32x4 acc[4] = {};
    #pragma unroll
    for (int s = 0; s < 8; s++) {
        int koff = s * 64 + lgr * 16;
        bf16x8 af = *(const bf16x8*)(As + arow * 512 + (koff ^ ((arow & 7) << 4)));
        #pragma unroll
        for (int ct = 0; ct < 4; ct++) {
            int brow = ct * 16 + lrow;
            bf16x8 bfr = *(const bf16x8*)(Bs + brow * 512 + (koff ^ ((brow & 7) << 4)));
            acc[ct] = MFMA16(af, bfr, acc[ct]);
        }
    }

    if (n0 < 512) {  // Q / K
        #pragma unroll
        for (int ct = 0; ct < 4; ct++) {
            int d = n0 + ct * 16 + lrow;
            float bias = qkv_b[d];
            #pragma unroll
            for (int r = 0; r < 4; r++) {
                int m = m0 + wv * 16 + lgr * 4 + r;
                float val = acc[ct][r] + bias;
                if (d < 256) qb[(size_t)m * 256 + d] = (bf16_t)val;
                else kb[(size_t)m * 256 + (d - 256)] = (bf16_t)val;
            }
        }
    } else {  // V: transpose through LDS, write (b, d, n)
        __syncthreads();
        bf16_t* tt = (bf16_t*)smem;  // 64 x 66 padded
        #pragma unroll
        for (int ct = 0; ct < 4; ct++) {
            int d = n0 + ct * 16 + lrow;
            float bias = qkv_b[d];
            #pragma unroll
            for (int r = 0; r < 4; r++)
                tt[(ct * 16 + lrow) * 66 + wv * 16 + lgr * 4 + r] = (bf16_t)(acc[ct][r] + bias);
        }
        __syncthreads();
        int bb = m0 >> 10, nbase = m0 & 1023;
        #pragma unroll
        for (int i = 0; i < 16; i++) {
            int e = i * 256 + tid;
            int d_l = e >> 6, m_l = e & 63;
            vt[(size_t)bb * 262144 + (size_t)(n0 - 512 + d_l) * 1024 + nbase + m_l] =
                tt[d_l * 66 + m_l];
        }
    }
}

// ---------------- K3: fused attention, 32x32 MFMA, swapped QK^T ----------------
// block: 128 q-rows (4 waves x 32), Tk=64, K/V double-buffered via global_load_lds.
// grid 256 (1 block/CU), XCD-swizzled so each XCD owns 4 batches' K/V in its L2.
__global__ __launch_bounds__(256) void attn_kernel(const bf16_t* __restrict__ qb,
                                                   const bf16_t* __restrict__ kb,
                                                   const bf16_t* __restrict__ vt,
                                                   bf16_t* __restrict__ ao) {
    extern __shared__ char smem[];  // K dbuf 2x32KB | V dbuf 2x32KB | P 4x4KB = 144KB
    int tid = threadIdx.x;
    int i = blockIdx.x;
    int b = (i & 7) + ((i >> 6) << 3);
    int qt = (i >> 3) & 7;
    int wv = tid >> 6, lane = tid & 63;
    int l31 = lane & 31, hi = lane >> 5;

    const char* kbase = (const char*)kb + (size_t)b * 524288;
    const char* vbase = (const char*)vt + (size_t)b * 524288;
    char* Pw = smem + 131072 + wv * 4096;

    // Q fragments for all 256 d: B-operand, lane holds Q[qg][ks*16 + hi*8 + j]
    int qg = qt * 128 + wv * 32 + l31;
    const char* qsrc = (const char*)qb + (size_t)(b * 1024 + qg) * 512;
    bf16x8 qf[16];
    #pragma unroll
    for (int ks = 0; ks < 16; ks++) qf[ks] = *(const bf16x8*)(qsrc + ks * 32 + hi * 16);

    f32x16 o[8] = {};
    float mrun = -1e30f, lrun = 0.f;

    // stage chunk ch into buffer buf (linear LDS dest, pre-swizzled global source)
    auto stage = [&](int buf, int ch) {
        int j0 = ch * 64;
        char* Kd = smem + buf * 32768;
        char* Vd = smem + 65536 + buf * 32768;
        #pragma unroll
        for (int t = 0; t < 8; t++) {  // K: 64 rows x 512B, 2 rows/instr
            int r0 = wv * 16 + t * 2;
            int r = r0 + (lane >> 5), u = lane & 31;
            const char* gp = kbase + (size_t)(j0 + r) * 512 + ((u ^ (r & 7)) * 16);
            GLL16(gp, Kd + r0 * 512);
        }
        #pragma unroll
        for (int t = 0; t < 8; t++) {  // V^T: 256 rows x 128B, 8 rows/instr
            int r0 = wv * 64 + t * 8;
            int r = r0 + (lane >> 3), u = lane & 7;
            const char* gp = vbase + (size_t)r * 2048 + j0 * 2 + ((u ^ (r & 7)) * 16);
            GLL16(gp, Vd + r0 * 128);
        }
    };

    stage(0, 0);
    __syncthreads();

    for (int ch = 0; ch < 16; ch++) {
        int cur = ch & 1;
        char* Ks = smem + cur * 32768;
        char* Vs = smem + 65536 + cur * 32768;
        if (ch < 15) stage(cur ^ 1, ch + 1);

        // S^T = K Q^T : A = K rows (k), B = Q cols (q). Lane: q=l31, k in-lane.
        f32x16 sc0 = {}, sc1 = {};
        #pragma unroll
        for (int ks = 0; ks < 16; ks++) {
            int col = ks * 32 + hi * 16;
            int r0 = l31, r1 = 32 + l31;
            bf16x8 k0 = *(const bf16x8*)(Ks + r0 * 512 + (col ^ ((r0 & 7) << 4)));
            bf16x8 k1 = *(const bf16x8*)(Ks + r1 * 512 + (col ^ ((r1 & 7) << 4)));
            sc0 = MFMA32(k0, qf[ks], sc0);
            sc1 = MFMA32(k1, qf[ks], sc1);
        }

        // online softmax (defer-max THR=8); all 64 keys in-lane except 1 shfl
        float sv0[16], sv1[16];
        float m_c = -1e30f;
        #pragma unroll
        for (int r = 0; r < 16; r++) {
            sv0[r] = sc0[r] * 0.0625f;
            sv1[r] = sc1[r] * 0.0625f;
            m_c = fmaxf(m_c, fmaxf(sv0[r], sv1[r]));
        }
        m_c = fmaxf(m_c, __shfl_xor(m_c, 32));
        float mo = mrun;
        float mn = (m_c <= mo + 8.0f) ? mo : m_c;
        float rs = 0.f;
        #pragma unroll
        for (int r = 0; r < 16; r++) {
            sv0[r] = __expf(sv0[r] - mn);
            sv1[r] = __expf(sv1[r] - mn);
            rs += sv0[r] + sv1[r];
        }
        rs += __shfl_xor(rs, 32);
        float alpha = __expf(mo - mn);
        lrun = lrun * alpha + rs;
        mrun = mn;
        // P[q][k] to LDS (swizzled): k = kt*32 + 8*rg + 4*hi + r
        #pragma unroll
        for (int rg = 0; rg < 4; rg++) {
            bf16x4 pa, pb;
            #pragma unroll
            for (int r = 0; r < 4; r++) {
                pa[r] = (bf16_t)sv0[rg * 4 + r];
                pb[r] = (bf16_t)sv1[rg * 4 + r];
            }
            int sw = (l31 & 7) << 4;
            *(bf16x4*)(Pw + l31 * 128 + ((rg * 16 + hi * 8) ^ sw)) = pa;
            *(bf16x4*)(Pw + l31 * 128 + ((64 + rg * 16 + hi * 8) ^ sw)) = pb;
        }
        if (__any(mn != mo)) {
            #pragma unroll
            for (int dt = 0; dt < 8; dt++) o[dt] = o[dt] * alpha;
        }

        // O^T += V^T P^T : A = V^T rows (d), B = P cols (q)
        #pragma unroll
        for (int ks = 0; ks < 4; ks++) {
            int pcol = (ks * 32 + hi * 16) ^ ((l31 & 7) << 4);
            bf16x8 pf = *(const bf16x8*)(Pw + l31 * 128 + pcol);
            #pragma unroll
            for (int dt = 0; dt < 8; dt++) {
                int d = dt * 32 + l31;
                bf16x8 vf =
                    *(const bf16x8*)(Vs + d * 128 + ((ks * 32 + hi * 16) ^ ((d & 7) << 4)));
                o[dt] = MFMA32(vf, pf, o[dt]);
            }
        }
        __syncthreads();  // drains vmcnt -> next buffer ready; all reads of cur done
    }

    float inv = 1.0f / lrun;
    char* aod = (char*)ao + (size_t)(b * 1024 + qg) * 512;
    #pragma unroll
    for (int dt = 0; dt < 8; dt++) {
        #pragma unroll
        for (int rg = 0; rg < 4; rg++) {
            bf16x4 w;
            #pragma unroll
            for (int r = 0; r < 4; r++) w[r] = (bf16_t)(o[dt][rg * 4 + r] * inv);
            *(bf16x4*)(aod + dt * 64 + rg * 16 + hi * 8) = w;
        }
    }
}

// ---------------- K4: out-proj GEMM + bias + residual ----------------
__global__ __launch_bounds__(256) void gemm_out(const bf16_t* __restrict__ wo,
                                                const bf16_t* __restrict__ ao,
                                                const float* __restrict__ out_b,
                                                const float* __restrict__ x,
                                                float* __restrict__ out) {
    __shared__ char smem[65536];
    char* As = smem;
    char* Bs = smem + 32768;
    int tid = threadIdx.x;
    int c0 = blockIdx.x * 64, n0 = blockIdx.y * 64, b = blockIdx.z;
    const char* asrc = (const char*)wo + (size_t)c0 * 512;
    const char* bsrc = (const char*)ao + ((size_t)b * 1024 + n0) * 512;

    float4 ta[8], tb[8];
    #pragma unroll
    for (int i = 0; i < 8; i++) {
        int t = i * 256 + tid, row = t >> 5, sl = t & 31;
        ta[i] = *(const float4*)(asrc + row * 512 + sl * 16);
        tb[i] = *(const float4*)(bsrc + row * 512 + sl * 16);
    }
    #pragma unroll
    for (int i = 0; i < 8; i++) {
        int t = i * 256 + tid, row = t >> 5, sl = t & 31;
        int off = (sl * 16) ^ ((row & 7) << 4);
        *(float4*)(As + row * 512 + off) = ta[i];
        *(float4*)(Bs + row * 512 + off) = tb[i];
    }
    __syncthreads();

    int wv = tid >> 6, lane = tid & 63, lrow = lane & 15, lgr = lane >> 4;
    int arow = wv * 16 + lrow;
    f32x4 acc[4] = {};
    #pragma unroll
    for (int s = 0; s < 8; s++) {
        int koff = s * 64 + lgr * 16;
        bf16x8 af = *(const bf16x8*)(As + arow * 512 + (koff ^ ((arow & 7) << 4)));
        #pragma unroll
        for (int ct = 0; ct < 4; ct++) {
            int brow = ct * 16 + lrow;
            bf16x8 bfr = *(const bf16x8*)(Bs + brow * 512 + (koff ^ ((brow & 7) << 4)));
            acc[ct] = MFMA16(af, bfr, acc[ct]);
        }
    }

    #pragma unroll
    for (int ct = 0; ct < 4; ct++) {
        int n = n0 + ct * 16 + lrow;
        #pragma unroll
        for (int r = 0; r < 4; r++) {
            int c = c0 + wv * 16 + lgr * 4 + r;
            size_t idx = ((size_t)b * 256 + c) * 1024 + n;
            out[idx] = acc[ct][r] + out_b[c] + x[idx];
        }
    }
}

// ---------------- launcher ----------------
extern "C" void kernel_launch(void* const* d_in, const int* in_sizes, int n_in,
                              void* d_out, int out_size, void* d_ws, size_t ws_size,
                              hipStream_t stream) {
    (void)in_sizes; (void)n_in; (void)out_size; (void)ws_size;
    const float* x      = (const float*)d_in[0];
    const float* gamma  = (const float*)d_in[1];
    const float* beta   = (const float*)d_in[2];
    const float* qkv_w  = (const float*)d_in[3];
    const float* qkv_b  = (const float*)d_in[4];
    const float* out_w  = (const float*)d_in[5];
    const float* out_b  = (const float*)d_in[6];
    float* out = (float*)d_out;

    char* ws = (char*)d_ws;
    const size_t MB16 = 16777216;
    bf16_t* xn  = (bf16_t*)(ws);             // (b, n, 256) bf16
    bf16_t* qb  = (bf16_t*)(ws + 1 * MB16);  // (b, n, 256)
    bf16_t* kb  = (bf16_t*)(ws + 2 * MB16);  // (b, n, 256)
    bf16_t* vt  = (bf16_t*)(ws + 3 * MB16);  // (b, 256, n)  V transposed
    bf16_t* ao  = (bf16_t*)(ws + 4 * MB16);  // (b, n, 256)
    bf16_t* wqb = (bf16_t*)(ws + 5 * MB16);            // 768x256 bf16
    bf16_t* wob = (bf16_t*)(ws + 5 * MB16 + 393216);   // 256x256 bf16

    cast_bf16<<<192, 256, 0, stream>>>(qkv_w, wqb, 196608);
    cast_bf16<<<64, 256, 0, stream>>>(out_w, wob, 65536);
    gn_kernel<<<256, 256, 65600, stream>>>(x, gamma, beta, xn);
    gemm_qkv<<<dim3(512, 12), 256, 0, stream>>>(xn, wqb, qkv_b, qb, kb, vt);
    attn_kernel<<<256, 256, 147456, stream>>>(qb, kb, vt, ao);
    gemm_out<<<dim3(4, 16, 32), 256, 0, stream>>>(wob, ao, out_b, x, out);
}

// Round 3
// 142.519 us; speedup vs baseline: 1.4259x; 1.0107x over previous
//
#include <hip/hip_runtime.h>
#include <hip/hip_bf16.h>
#include <stdint.h>

// AttentionBlock: GN(8) -> qkv 1x1 -> attention(1024 tok, d=256) -> proj -> +x
// b=32, c=256, h=w=32 (hw=1024). fp32 in/out; bf16 MFMA internally.

typedef __bf16 bf16_t;
typedef __bf16 bf16x4 __attribute__((ext_vector_type(4)));
typedef __bf16 bf16x8 __attribute__((ext_vector_type(8)));
typedef float f32x4 __attribute__((ext_vector_type(4)));
typedef float f32x16 __attribute__((ext_vector_type(16)));
typedef _Float16 f16x4 __attribute__((ext_vector_type(4)));

#define MFMA32(a, b, c) __builtin_amdgcn_mfma_f32_32x32x16_bf16((a), (b), (c), 0, 0, 0)
#define GLL16(g, l)                                                                     \
    __builtin_amdgcn_global_load_lds((const __attribute__((address_space(1))) void*)(g), \
                                     (__attribute__((address_space(3))) void*)(l), 16, 0, 0)
#define WAITV8 asm volatile("s_waitcnt vmcnt(8)" ::: "memory")
#define WAITV0 asm volatile("s_waitcnt vmcnt(0)" ::: "memory")
#define WLG0   asm volatile("s_waitcnt lgkmcnt(0)" ::: "memory")
#define SBAR   __builtin_amdgcn_s_barrier()
#define SCH0   __builtin_amdgcn_sched_barrier(0)

// Q pre-scale: (1/sqrt(256)) * log2(e)  -> softmax in exp2 domain
#define QSCALE 0.0901684400555f

__device__ inline uint32_t pack2(float a, float b) {
    union { uint32_t u; __bf16 h[2]; } w;
    w.h[0] = (__bf16)a; w.h[1] = (__bf16)b;
    return w.u;
}

// ---------------- K0: fp32 -> bf16 cast (weights) ----------------
__global__ void cast_bf16(const float* __restrict__ s, bf16_t* __restrict__ d, int n) {
    for (int i = blockIdx.x * blockDim.x + threadIdx.x; i < n; i += gridDim.x * blockDim.x)
        d[i] = (bf16_t)s[i];
}

// ---------------- K1: GroupNorm + transpose to (b, pixel, c) bf16 ----------------
__global__ __launch_bounds__(256) void gn_kernel(const float* __restrict__ x,
                                                 const float* __restrict__ gamma,
                                                 const float* __restrict__ beta,
                                                 bf16_t* __restrict__ xn) {
    extern __shared__ char gsm[];  // 65536 (fp16 stash) + 64 (reduce)
    float* red = (float*)(gsm + 65536);
    int bg = blockIdx.x, b = bg >> 3, g = bg & 7;
    const float* base = x + (size_t)(b * 256 + g * 32) * 1024;
    int tid = threadIdx.x;

    float s = 0.f, ss = 0.f;
    #pragma unroll 4
    for (int c = 0; c < 32; c++) {
        float4 v = *(const float4*)(base + c * 1024 + tid * 4);
        s += v.x + v.y + v.z + v.w;
        ss += v.x * v.x + v.y * v.y + v.z * v.z + v.w * v.w;
        f16x4 h = {(_Float16)v.x, (_Float16)v.y, (_Float16)v.z, (_Float16)v.w};
        *(f16x4*)(gsm + c * 2048 + ((tid * 8) ^ ((c & 7) << 4))) = h;
    }
    for (int off = 32; off; off >>= 1) { s += __shfl_down(s, off); ss += __shfl_down(ss, off); }
    if ((tid & 63) == 0) { red[tid >> 6] = s; red[4 + (tid >> 6)] = ss; }
    __syncthreads();
    float S = red[0] + red[1] + red[2] + red[3];
    float SS = red[4] + red[5] + red[6] + red[7];
    float mean = S * (1.0f / 32768.0f);
    float var = SS * (1.0f / 32768.0f) - mean * mean;
    float rstd = rsqrtf(var + 1e-5f);

    int c = tid & 31;
    float gam = gamma[g * 32 + c] * rstd;
    float bet = beta[g * 32 + c] - mean * gam;
    bf16_t* dst = xn + (size_t)(b * 1024) * 256 + g * 32 + c;
    #pragma unroll 4
    for (int it = 0; it < 128; it++) {
        int p = it * 8 + (tid >> 5);
        _Float16 hv = *(_Float16*)(gsm + c * 2048 + ((p * 2) ^ ((c & 7) << 4)));
        dst[(size_t)p * 256] = (bf16_t)((float)hv * gam + bet);
    }
}

// ======== shared GEMM pieces: 128x128 tile, K=256, 4 waves, wave-tile 64x64 ========
// Stage 128 rows x 512B into LDS (linear dest, pre-swizzled global source).
__device__ inline void stage128(const char* src, char* dstLDS, int wv, int lane) {
    int r2 = lane >> 5, u = lane & 31;
    #pragma unroll
    for (int t = 0; t < 16; t++) {
        int row = t * 8 + wv * 2 + r2;
        GLL16(src + (size_t)row * 512 + ((u ^ (row & 7)) * 16), dstLDS + (t * 8 + wv * 2) * 512);
    }
}
__device__ inline bf16x8 lds_frag(const char* base, int row, int sl) {
    return *(const bf16x8*)(base + row * 512 + ((sl ^ (row & 7)) * 16));
}

// ---------------- K2a: Q/K GEMM: C[m,d] = xn[m,:]·wq[d,:] + b, d in [0,512) --------
__global__ __launch_bounds__(256) void gemm_qk(const bf16_t* __restrict__ xn,
                                               const bf16_t* __restrict__ wq,
                                               const float* __restrict__ qkv_b,
                                               bf16_t* __restrict__ qb,
                                               bf16_t* __restrict__ kb) {
    extern __shared__ char smem[];  // 128KB: A | B
    char* As = smem; char* Bs = smem + 65536;
    int tid = threadIdx.x, wv = tid >> 6, lane = tid & 63;
    int m0 = blockIdx.x * 128, n0 = blockIdx.y * 128;
    stage128((const char*)xn + (size_t)m0 * 512, As, wv, lane);
    stage128((const char*)wq + (size_t)n0 * 512, Bs, wv, lane);
    __syncthreads();

    int wr = wv >> 1, wc = wv & 1, l31 = lane & 31, hi = lane >> 5;
    f32x16 acc[2][2] = {};
    #pragma unroll
    for (int ks = 0; ks < 16; ks++) {
        int sl = ks * 2 + hi;
        bf16x8 a0 = lds_frag(As, wr * 64 + l31, sl);
        bf16x8 a1 = lds_frag(As, wr * 64 + 32 + l31, sl);
        bf16x8 b0 = lds_frag(Bs, wc * 64 + l31, sl);
        bf16x8 b1 = lds_frag(Bs, wc * 64 + 32 + l31, sl);
        acc[0][0] = MFMA32(a0, b0, acc[0][0]);
        acc[0][1] = MFMA32(a0, b1, acc[0][1]);
        acc[1][0] = MFMA32(a1, b0, acc[1][0]);
        acc[1][1] = MFMA32(a1, b1, acc[1][1]);
    }
    #pragma unroll
    for (int ms = 0; ms < 2; ms++)
        #pragma unroll
        for (int ns = 0; ns < 2; ns++) {
            int n = n0 + wc * 64 + ns * 32 + l31;
            float bias = qkv_b[n];
            bool isq = n < 256;
            float sc = isq ? QSCALE : 1.0f;
            bf16_t* dst = isq ? qb : kb;
            int d = isq ? n : n - 256;
            #pragma unroll
            for (int r = 0; r < 16; r++) {
                int m = m0 + wr * 64 + ms * 32 + (r & 3) + 8 * (r >> 2) + 4 * hi;
                dst[(size_t)m * 256 + d] = (bf16_t)((acc[ms][ns][r] + bias) * sc);
            }
        }
}

// ---------------- K2b: V GEMM (swapped operands) -> vt (b, d, n) ----------------
__global__ __launch_bounds__(256) void gemm_v(const bf16_t* __restrict__ xn,
                                              const bf16_t* __restrict__ wq,
                                              const float* __restrict__ qkv_b,
                                              bf16_t* __restrict__ vt) {
    extern __shared__ char smem[];
    char* As = smem; char* Bs = smem + 65536;  // A = w rows (512+d), B = xn rows (tok)
    int tid = threadIdx.x, wv = tid >> 6, lane = tid & 63;
    int d0 = blockIdx.x * 128, t0 = blockIdx.y * 128;
    stage128((const char*)wq + (size_t)(512 + d0) * 512, As, wv, lane);
    stage128((const char*)xn + (size_t)t0 * 512, Bs, wv, lane);
    __syncthreads();

    int wr = wv >> 1, wc = wv & 1, l31 = lane & 31, hi = lane >> 5;
    f32x16 acc[2][2] = {};
    #pragma unroll
    for (int ks = 0; ks < 16; ks++) {
        int sl = ks * 2 + hi;
        bf16x8 a0 = lds_frag(As, wr * 64 + l31, sl);
        bf16x8 a1 = lds_frag(As, wr * 64 + 32 + l31, sl);
        bf16x8 b0 = lds_frag(Bs, wc * 64 + l31, sl);
        bf16x8 b1 = lds_frag(Bs, wc * 64 + 32 + l31, sl);
        acc[0][0] = MFMA32(a0, b0, acc[0][0]);
        acc[0][1] = MFMA32(a0, b1, acc[0][1]);
        acc[1][0] = MFMA32(a1, b0, acc[1][0]);
        acc[1][1] = MFMA32(a1, b1, acc[1][1]);
    }
    #pragma unroll
    for (int ms = 0; ms < 2; ms++)
        #pragma unroll
        for (int ns = 0; ns < 2; ns++) {
            int tok0 = t0 + wc * 64 + ns * 32;  // + l31 per lane
            #pragma unroll
            for (int r = 0; r < 16; r++) {
                int d = d0 + wr * 64 + ms * 32 + (r & 3) + 8 * (r >> 2) + 4 * hi;
                int tok = tok0 + l31;
                int bb = tok >> 10, pos = tok & 1023;
                vt[(size_t)bb * 262144 + (size_t)d * 1024 + pos] =
                    (bf16_t)(acc[ms][ns][r] + qkv_b[512 + d]);
            }
        }
}

// ---------------- K4: out-proj GEMM + bias + residual ----------------
__global__ __launch_bounds__(256) void gemm_out(const bf16_t* __restrict__ wo,
                                                const bf16_t* __restrict__ ao,
                                                const float* __restrict__ out_b,
                                                const float* __restrict__ x,
                                                float* __restrict__ out) {
    extern __shared__ char smem[];
    char* As = smem; char* Bs = smem + 65536;  // A = wo rows (c), B = ao rows (tok)
    int tid = threadIdx.x, wv = tid >> 6, lane = tid & 63;
    int c0 = blockIdx.x * 128, t0 = blockIdx.y * 128;
    stage128((const char*)wo + (size_t)c0 * 512, As, wv, lane);
    stage128((const char*)ao + (size_t)t0 * 512, Bs, wv, lane);
    __syncthreads();

    int wr = wv >> 1, wc = wv & 1, l31 = lane & 31, hi = lane >> 5;
    f32x16 acc[2][2] = {};
    #pragma unroll
    for (int ks = 0; ks < 16; ks++) {
        int sl = ks * 2 + hi;
        bf16x8 a0 = lds_frag(As, wr * 64 + l31, sl);
        bf16x8 a1 = lds_frag(As, wr * 64 + 32 + l31, sl);
        bf16x8 b0 = lds_frag(Bs, wc * 64 + l31, sl);
        bf16x8 b1 = lds_frag(Bs, wc * 64 + 32 + l31, sl);
        acc[0][0] = MFMA32(a0, b0, acc[0][0]);
        acc[0][1] = MFMA32(a0, b1, acc[0][1]);
        acc[1][0] = MFMA32(a1, b0, acc[1][0]);
        acc[1][1] = MFMA32(a1, b1, acc[1][1]);
    }
    #pragma unroll
    for (int ms = 0; ms < 2; ms++)
        #pragma unroll
        for (int ns = 0; ns < 2; ns++) {
            #pragma unroll
            for (int r = 0; r < 16; r++) {
                int c = c0 + wr * 64 + ms * 32 + (r & 3) + 8 * (r >> 2) + 4 * hi;
                int tok = t0 + wc * 64 + ns * 32 + l31;
                int bb = tok >> 10, pos = tok & 1023;
                size_t idx = ((size_t)bb * 256 + c) * 1024 + pos;
                out[idx] = acc[ms][ns][r] + out_b[c] + x[idx];
            }
        }
}

// ---------------- K3: fused attention, pipelined, in-register P ----------------
// 256 blocks (1/CU), 4 waves x 32 q-rows, Tk=64. K/V dbuf via global_load_lds with
// counted vmcnt(8); iter body: QKT(ch) || softmax(ch-1) || PV(ch-1).
__global__ __launch_bounds__(256, 1) void attn_kernel(const bf16_t* __restrict__ qb,
                                                      const bf16_t* __restrict__ kb,
                                                      const bf16_t* __restrict__ vt,
                                                      bf16_t* __restrict__ ao) {
    extern __shared__ char smem[];  // K dbuf 2x32KB @0 | V dbuf 2x32KB @65536
    int tid = threadIdx.x, i = blockIdx.x;
    int b = (i & 7) + ((i >> 6) << 3);
    int qt = (i >> 3) & 7;
    int wv = tid >> 6, lane = tid & 63, l31 = lane & 31, hi = lane >> 5;

    const char* kbase = (const char*)kb + (size_t)b * 524288;
    const char* vbase = (const char*)vt + (size_t)b * 524288;

    int qg = qt * 128 + wv * 32 + l31;
    const char* qsrc = (const char*)qb + (size_t)(b * 1024 + qg) * 512;
    bf16x8 qf[16];
    #pragma unroll
    for (int ks = 0; ks < 16; ks++) qf[ks] = *(const bf16x8*)(qsrc + ks * 32 + hi * 16);

    f32x16 o[8] = {};
    f32x16 sp0 = {}, sp1 = {};
    float mrun = -1e30f, lrun = 0.f;

    auto stage_K = [&](int ch) {
        char* Kd = smem + (ch & 1) * 32768;
        int j0 = ch * 64;
        #pragma unroll
        for (int t = 0; t < 8; t++) {
            int r0 = wv * 16 + t * 2;
            int r = r0 + (lane >> 5), u = lane & 31;
            GLL16(kbase + (size_t)(j0 + r) * 512 + ((u ^ (r & 7)) * 16), Kd + r0 * 512);
        }
    };
    auto stage_V = [&](int ch) {
        char* Vd = smem + 65536 + (ch & 1) * 32768;
        int j0 = ch * 64;
        #pragma unroll
        for (int t = 0; t < 8; t++) {
            int r0 = wv * 64 + t * 8;
            int r = r0 + (lane >> 3), u = lane & 7;
            GLL16(vbase + (size_t)r * 2048 + j0 * 2 + ((u ^ (r & 7)) * 16), Vd + r0 * 128);
        }
    };
    auto qkt = [&](int ch, f32x16& s0, f32x16& s1) {
        const char* Ks = smem + (ch & 1) * 32768;
        #pragma unroll
        for (int ks = 0; ks < 16; ks++) {
            int col = ks * 32 + hi * 16;
            bf16x8 k0 = *(const bf16x8*)(Ks + l31 * 512 + (col ^ ((l31 & 7) << 4)));
            bf16x8 k1 = *(const bf16x8*)(Ks + (32 + l31) * 512 + (col ^ ((l31 & 7) << 4)));
            s0 = MFMA32(k0, qf[ks], s0);
            s1 = MFMA32(k1, qf[ks], s1);
        }
    };
    auto smax_pv = [&](int ch) {  // softmax on sp0/sp1, then PV with V[ch&1]
        float mc = -1e30f;
        #pragma unroll
        for (int r = 0; r < 16; r++) mc = fmaxf(mc, fmaxf(sp0[r], sp1[r]));
        mc = fmaxf(mc, __shfl_xor(mc, 32));
        float mo = mrun;
        float mn = (mc <= mo + 8.0f) ? mo : mc;
        float rs = 0.f;
        #pragma unroll
        for (int r = 0; r < 16; r++) {
            sp0[r] = exp2f(sp0[r] - mn);
            sp1[r] = exp2f(sp1[r] - mn);
            rs += sp0[r] + sp1[r];
        }
        rs += __shfl_xor(rs, 32);
        float al = exp2f(mo - mn);
        lrun = lrun * al + rs;
        mrun = mn;
        if (__any(mn != mo)) {
            #pragma unroll
            for (int dt = 0; dt < 8; dt++) o[dt] = o[dt] * al;
        }
        const char* Vs = smem + 65536 + (ch & 1) * 32768;
        #pragma unroll
        for (int pk = 0; pk < 4; pk++) {
            float e0 = (pk < 2) ? sp0[(pk & 1) * 8 + 0] : sp1[(pk & 1) * 8 + 0];
            float e1 = (pk < 2) ? sp0[(pk & 1) * 8 + 1] : sp1[(pk & 1) * 8 + 1];
            float e2 = (pk < 2) ? sp0[(pk & 1) * 8 + 2] : sp1[(pk & 1) * 8 + 2];
            float e3 = (pk < 2) ? sp0[(pk & 1) * 8 + 3] : sp1[(pk & 1) * 8 + 3];
            float e4 = (pk < 2) ? sp0[(pk & 1) * 8 + 4] : sp1[(pk & 1) * 8 + 4];
            float e5 = (pk < 2) ? sp0[(pk & 1) * 8 + 5] : sp1[(pk & 1) * 8 + 5];
            float e6 = (pk < 2) ? sp0[(pk & 1) * 8 + 6] : sp1[(pk & 1) * 8 + 6];
            float e7 = (pk < 2) ? sp0[(pk & 1) * 8 + 7] : sp1[(pk & 1) * 8 + 7];
            uint32_t A0 = pack2(e0, e1), A1 = pack2(e2, e3);
            uint32_t B0 = pack2(e4, e5), B1 = pack2(e6, e7);
            asm volatile("v_permlane32_swap_b32 %0, %1" : "+v"(B0), "+v"(A0));
            asm volatile("v_permlane32_swap_b32 %0, %1" : "+v"(B1), "+v"(A1));
            union { bf16x8 v; uint32_t u[4]; } pw;
            pw.u[0] = A0; pw.u[1] = A1; pw.u[2] = B0; pw.u[3] = B1;
            #pragma unroll
            for (int dt = 0; dt < 8; dt++) {
                int d = dt * 32 + l31;
                bf16x8 vf =
                    *(const bf16x8*)(Vs + d * 128 + ((pk * 32 + hi * 16) ^ ((d & 7) << 4)));
                o[dt] = MFMA32(vf, pw.v, o[dt]);
            }
        }
    };

    // prologue
    stage_K(0); stage_V(0);
    WAITV8; SCH0; SBAR;
    stage_K(1);
    qkt(0, sp0, sp1);
    WLG0; SCH0; SBAR;
    stage_V(1);

    for (int ch = 1; ch < 16; ch++) {
        WAITV8; SCH0; SBAR;
        if (ch < 15) stage_K(ch + 1);
        f32x16 sn0 = {}, sn1 = {};
        qkt(ch, sn0, sn1);
        smax_pv(ch - 1);
        WLG0; SCH0; SBAR;
        if (ch < 15) stage_V(ch + 1);
        sp0 = sn0; sp1 = sn1;
    }
    WAITV0; SCH0; SBAR;
    smax_pv(15);

    float inv = 1.0f / lrun;
    char* aod = (char*)ao + (size_t)(b * 1024 + qg) * 512;
    #pragma unroll
    for (int dt = 0; dt < 8; dt++) {
        #pragma unroll
        for (int rg = 0; rg < 4; rg++) {
            bf16x4 w;
            #pragma unroll
            for (int r = 0; r < 4; r++) w[r] = (bf16_t)(o[dt][rg * 4 + r] * inv);
            *(bf16x4*)(aod + dt * 64 + rg * 16 + hi * 8) = w;
        }
    }
}

// ---------------- launcher ----------------
extern "C" void kernel_launch(void* const* d_in, const int* in_sizes, int n_in,
                              void* d_out, int out_size, void* d_ws, size_t ws_size,
                              hipStream_t stream) {
    (void)in_sizes; (void)n_in; (void)out_size; (void)ws_size;
    const float* x      = (const float*)d_in[0];
    const float* gamma  = (const float*)d_in[1];
    const float* beta   = (const float*)d_in[2];
    const float* qkv_w  = (const float*)d_in[3];
    const float* qkv_b  = (const float*)d_in[4];
    const float* out_w  = (const float*)d_in[5];
    const float* out_b  = (const float*)d_in[6];
    float* out = (float*)d_out;

    char* ws = (char*)d_ws;
    const size_t MB16 = 16777216;
    bf16_t* xn  = (bf16_t*)(ws);             // (b, n, 256) bf16
    bf16_t* qb  = (bf16_t*)(ws + 1 * MB16);  // (b, n, 256)  pre-scaled by QSCALE
    bf16_t* kb  = (bf16_t*)(ws + 2 * MB16);  // (b, n, 256)
    bf16_t* vt  = (bf16_t*)(ws + 3 * MB16);  // (b, 256, n)  V transposed
    bf16_t* ao  = (bf16_t*)(ws + 4 * MB16);  // (b, n, 256)
    bf16_t* wqb = (bf16_t*)(ws + 5 * MB16);            // 768x256 bf16
    bf16_t* wob = (bf16_t*)(ws + 5 * MB16 + 393216);   // 256x256 bf16

    cast_bf16<<<192, 256, 0, stream>>>(qkv_w, wqb, 196608);
    cast_bf16<<<64, 256, 0, stream>>>(out_w, wob, 65536);
    gn_kernel<<<256, 256, 65600, stream>>>(x, gamma, beta, xn);
    gemm_qk<<<dim3(256, 4), 256, 131072, stream>>>(xn, wqb, qkv_b, qb, kb);
    gemm_v<<<dim3(2, 256), 256, 131072, stream>>>(xn, wqb, qkv_b, vt);
    attn_kernel<<<256, 256, 131072, stream>>>(qb, kb, vt, ao);
    gemm_out<<<dim3(2, 256), 256, 131072, stream>>>(wob, ao, out_b, x, out);
}

// Round 4
// 138.684 us; speedup vs baseline: 1.4653x; 1.0277x over previous
//
#include <hip/hip_runtime.h>
#include <hip/hip_bf16.h>
#include <stdint.h>

// AttentionBlock: GN(8) -> qkv 1x1 -> attention(1024 tok, d=256) -> proj -> +x
// b=32, c=256, h=w=32 (hw=1024). fp32 in/out; bf16 MFMA internally.

typedef __bf16 bf16_t;
typedef __bf16 bf16x4 __attribute__((ext_vector_type(4)));
typedef __bf16 bf16x8 __attribute__((ext_vector_type(8)));
typedef float f32x16 __attribute__((ext_vector_type(16)));
typedef _Float16 f16x4 __attribute__((ext_vector_type(4)));

#define MFMA32(a, b, c) __builtin_amdgcn_mfma_f32_32x32x16_bf16((a), (b), (c), 0, 0, 0)
#define GLL16(g, l)                                                                      \
    __builtin_amdgcn_global_load_lds((const __attribute__((address_space(1))) void*)(g), \
                                     (__attribute__((address_space(3))) void*)(l), 16, 0, 0)
#define WAITV8 asm volatile("s_waitcnt vmcnt(8)" ::: "memory")
#define WAITV0 asm volatile("s_waitcnt vmcnt(0)" ::: "memory")
#define WLG0   asm volatile("s_waitcnt lgkmcnt(0)" ::: "memory")
#define SBAR   __builtin_amdgcn_s_barrier()

// Q pre-scale: (1/sqrt(256)) * log2(e)  -> softmax in exp2 domain
#define QSCALE 0.0901684400555f

__device__ inline uint32_t pack2(float a, float b) {
    union { uint32_t u; __bf16 h[2]; } w;
    w.h[0] = (__bf16)a; w.h[1] = (__bf16)b;
    return w.u;
}

// ---------------- K0: fp32 -> bf16 cast (both weight tensors, one launch) ----------
__global__ void cast_w(const float* __restrict__ s1, bf16_t* __restrict__ d1, int n1,
                       const float* __restrict__ s2, bf16_t* __restrict__ d2, int n2) {
    int i = blockIdx.x * blockDim.x + threadIdx.x;
    int stride = gridDim.x * blockDim.x;
    for (int k = i; k < n1; k += stride) d1[k] = (bf16_t)s1[k];
    for (int k = i; k < n2; k += stride) d2[k] = (bf16_t)s2[k];
}

// ---------------- K1: GroupNorm + transpose to (b, pixel, c) bf16 ----------------
__global__ __launch_bounds__(256) void gn_kernel(const float* __restrict__ x,
                                                 const float* __restrict__ gamma,
                                                 const float* __restrict__ beta,
                                                 bf16_t* __restrict__ xn) {
    extern __shared__ char gsm[];  // 65536 (fp16 stash) + 64 (reduce)
    float* red = (float*)(gsm + 65536);
    int bg = blockIdx.x, b = bg >> 3, g = bg & 7;
    const float* base = x + (size_t)(b * 256 + g * 32) * 1024;
    int tid = threadIdx.x;

    float s = 0.f, ss = 0.f;
    #pragma unroll 4
    for (int c = 0; c < 32; c++) {
        float4 v = *(const float4*)(base + c * 1024 + tid * 4);
        s += v.x + v.y + v.z + v.w;
        ss += v.x * v.x + v.y * v.y + v.z * v.z + v.w * v.w;
        f16x4 h = {(_Float16)v.x, (_Float16)v.y, (_Float16)v.z, (_Float16)v.w};
        *(f16x4*)(gsm + c * 2048 + ((tid * 8) ^ ((c & 7) << 4))) = h;
    }
    for (int off = 32; off; off >>= 1) { s += __shfl_down(s, off); ss += __shfl_down(ss, off); }
    if ((tid & 63) == 0) { red[tid >> 6] = s; red[4 + (tid >> 6)] = ss; }
    __syncthreads();
    float S = red[0] + red[1] + red[2] + red[3];
    float SS = red[4] + red[5] + red[6] + red[7];
    float mean = S * (1.0f / 32768.0f);
    float var = SS * (1.0f / 32768.0f) - mean * mean;
    float rstd = rsqrtf(var + 1e-5f);

    int c = tid & 31;
    float gam = gamma[g * 32 + c] * rstd;
    float bet = beta[g * 32 + c] - mean * gam;
    bf16_t* dst = xn + (size_t)(b * 1024) * 256 + g * 32 + c;
    #pragma unroll 4
    for (int it = 0; it < 128; it++) {
        int p = it * 8 + (tid >> 5);
        _Float16 hv = *(_Float16*)(gsm + c * 2048 + ((p * 2) ^ ((c & 7) << 4)));
        dst[(size_t)p * 256] = (bf16_t)((float)hv * gam + bet);
    }
}

// ---------------- K2: merged QKV GEMM ----------------
// grid 256 token-tiles of 128. Stage A (tokens) once; loop 12 weight tiles (64 rows)
// double-buffered. Q/K tiles: D[tok][d] (lanes=d). V tiles: swapped operands ->
// D[d][tok] (lanes=tok) -> coalesced vt stores.
__global__ __launch_bounds__(256, 1) void gemm_qkv(const bf16_t* __restrict__ xn,
                                                   const bf16_t* __restrict__ wq,
                                                   const float* __restrict__ qkv_b,
                                                   bf16_t* __restrict__ qb,
                                                   bf16_t* __restrict__ kb,
                                                   bf16_t* __restrict__ vt) {
    extern __shared__ char smem[];  // As 64KB | B dbuf 2x32KB
    char* As = smem;
    int tid = threadIdx.x, wv = tid >> 6, lane = tid & 63;
    int l31 = lane & 31, hi = lane >> 5;
    int t0 = blockIdx.x * 128;
    const char* asrc = (const char*)xn + (size_t)t0 * 512;
    const char* wsrc = (const char*)wq;

    {
        int u = lane & 31, rofs = lane >> 5;
        #pragma unroll
        for (int t = 0; t < 16; t++) {
            int r0 = t * 8 + wv * 2;
            int r = r0 + rofs;
            GLL16(asrc + (size_t)r * 512 + ((u ^ (r & 31)) * 16), As + r0 * 512);
        }
    }
    auto stage_B = [&](int nt) {
        char* Bd = smem + 65536 + (nt & 1) * 32768;
        int u = lane & 31, rofs = lane >> 5;
        #pragma unroll
        for (int t = 0; t < 8; t++) {
            int r0 = wv * 16 + t * 2;
            int r = r0 + rofs;
            GLL16(wsrc + (size_t)(nt * 64 + r) * 512 + ((u ^ (r & 31)) * 16), Bd + r0 * 512);
        }
    };
    stage_B(0);
    WAITV0; SBAR;

    int wm = wv >> 1, wd = wv & 1;
    int bb = t0 >> 10, pos0 = t0 & 1023;

    for (int nt = 0; nt < 12; nt++) {
        if (nt < 11) stage_B(nt + 1);
        const char* Bs = smem + 65536 + (nt & 1) * 32768;
        f32x16 acc0 = {}, acc1 = {};
        if (nt < 8) {
            __builtin_amdgcn_s_setprio(1);
            #pragma unroll
            for (int ks = 0; ks < 16; ks++) {
                int col = ks * 32 + hi * 16;
                bf16x8 a0 = *(const bf16x8*)(As + (wm * 64 + l31) * 512 + (col ^ (l31 << 4)));
                bf16x8 a1 = *(const bf16x8*)(As + (wm * 64 + 32 + l31) * 512 + (col ^ (l31 << 4)));
                bf16x8 b  = *(const bf16x8*)(Bs + (wd * 32 + l31) * 512 + (col ^ (l31 << 4)));
                acc0 = MFMA32(a0, b, acc0);
                acc1 = MFMA32(a1, b, acc1);
            }
            __builtin_amdgcn_s_setprio(0);
            int d = nt * 64 + wd * 32 + l31;
            bool isq = nt < 4;
            float bias = qkv_b[d];
            bf16_t* dst = isq ? qb : kb;
            int dd = isq ? d : d - 256;
            float sc = isq ? QSCALE : 1.0f;
            #pragma unroll
            for (int ms = 0; ms < 2; ms++) {
                #pragma unroll
                for (int r = 0; r < 16; r++) {
                    float v = ms ? acc1[r] : acc0[r];
                    int tok = t0 + wm * 64 + ms * 32 + (r & 3) + 8 * (r >> 2) + 4 * hi;
                    dst[(size_t)tok * 256 + dd] = (bf16_t)((v + bias) * sc);
                }
            }
        } else {
            __builtin_amdgcn_s_setprio(1);
            #pragma unroll
            for (int ks = 0; ks < 16; ks++) {
                int col = ks * 32 + hi * 16;
                bf16x8 a0 = *(const bf16x8*)(As + (wm * 64 + l31) * 512 + (col ^ (l31 << 4)));
                bf16x8 a1 = *(const bf16x8*)(As + (wm * 64 + 32 + l31) * 512 + (col ^ (l31 << 4)));
                bf16x8 b  = *(const bf16x8*)(Bs + (wd * 32 + l31) * 512 + (col ^ (l31 << 4)));
                acc0 = MFMA32(b, a0, acc0);
                acc1 = MFMA32(b, a1, acc1);
            }
            __builtin_amdgcn_s_setprio(0);
            int dbase = (nt - 8) * 64 + wd * 32;
            #pragma unroll
            for (int ms = 0; ms < 2; ms++) {
                int pos = pos0 + wm * 64 + ms * 32 + l31;
                #pragma unroll
                for (int r = 0; r < 16; r++) {
                    float v = ms ? acc1[r] : acc0[r];
                    int d = dbase + (r & 3) + 8 * (r >> 2) + 4 * hi;
                    vt[(size_t)bb * 262144 + (size_t)d * 1024 + pos] =
                        (bf16_t)(v + qkv_b[512 + d]);
                }
            }
        }
        if (nt < 11) { WAITV0; SBAR; }
    }
}

// ---------------- K3: fused attention, pipelined, in-register P ----------------
// 256 blocks (1/CU), 4 waves x 32 q-rows, Tk=64. K/V dbuf via global_load_lds with
// counted vmcnt(8); iter body: QKT(ch) || softmax(ch-1) || PV(ch-1).
// K swizzle: 32-slot XOR (r&31). V swizzle: flat a ^= ((a>>9)&31)<<4 (involution).
__global__ __launch_bounds__(256, 1) void attn_kernel(const bf16_t* __restrict__ qb,
                                                      const bf16_t* __restrict__ kb,
                                                      const bf16_t* __restrict__ vt,
                                                      bf16_t* __restrict__ ao) {
    extern __shared__ char smem[];  // K dbuf 2x32KB @0 | V dbuf 2x32KB @65536
    int tid = threadIdx.x, i = blockIdx.x;
    int b = (i & 7) + ((i >> 6) << 3);
    int qt = (i >> 3) & 7;
    int wv = tid >> 6, lane = tid & 63, l31 = lane & 31, hi = lane >> 5;

    const char* kbase = (const char*)kb + (size_t)b * 524288;
    const char* vbase = (const char*)vt + (size_t)b * 524288;

    int qg = qt * 128 + wv * 32 + l31;
    const char* qsrc = (const char*)qb + (size_t)(b * 1024 + qg) * 512;
    bf16x8 qf[16];
    #pragma unroll
    for (int ks = 0; ks < 16; ks++) qf[ks] = *(const bf16x8*)(qsrc + ks * 32 + hi * 16);

    f32x16 o[8] = {};
    f32x16 sp0 = {}, sp1 = {};
    float mrun = -1e30f, lrun = 0.f;

    auto stage_K = [&](int ch) {
        char* Kd = smem + (ch & 1) * 32768;
        int j0 = ch * 64;
        #pragma unroll
        for (int t = 0; t < 8; t++) {
            int r0 = wv * 16 + t * 2;
            int r = r0 + (lane >> 5), u = lane & 31;
            GLL16(kbase + (size_t)(j0 + r) * 512 + ((u ^ (r & 31)) * 16), Kd + r0 * 512);
        }
    };
    auto stage_V = [&](int ch) {
        char* Vd = smem + 65536 + (ch & 1) * 32768;
        int j0 = ch * 64;
        #pragma unroll
        for (int t = 0; t < 8; t++) {
            int r0 = wv * 64 + t * 8;
            int r = r0 + (lane >> 3), u = lane & 7;
            int s5 = (((r & 3) << 3) | u) ^ ((r >> 2) & 31);
            int d_src = (r & ~3) | (s5 >> 3);
            GLL16(vbase + (size_t)d_src * 2048 + j0 * 2 + (s5 & 7) * 16, Vd + r0 * 128);
        }
    };
    auto qkt = [&](int ch, f32x16& s0, f32x16& s1) {
        const char* Ks = smem + (ch & 1) * 32768;
        __builtin_amdgcn_s_setprio(1);
        #pragma unroll
        for (int ks = 0; ks < 16; ks++) {
            int col = ks * 32 + hi * 16;
            bf16x8 k0 = *(const bf16x8*)(Ks + l31 * 512 + (col ^ (l31 << 4)));
            bf16x8 k1 = *(const bf16x8*)(Ks + (32 + l31) * 512 + (col ^ (l31 << 4)));
            s0 = MFMA32(k0, qf[ks], s0);
            s1 = MFMA32(k1, qf[ks], s1);
        }
        __builtin_amdgcn_s_setprio(0);
    };
    auto smax_pv = [&](f32x16& t0v, f32x16& t1v, int ch) {
        float mc = -1e30f;
        #pragma unroll
        for (int r = 0; r < 16; r++) mc = fmaxf(mc, fmaxf(t0v[r], t1v[r]));
        mc = fmaxf(mc, __shfl_xor(mc, 32));
        float mo = mrun;
        float mn = (mc <= mo + 8.0f) ? mo : mc;
        float rs = 0.f;
        #pragma unroll
        for (int r = 0; r < 16; r++) {
            t0v[r] = exp2f(t0v[r] - mn);
            t1v[r] = exp2f(t1v[r] - mn);
            rs += t0v[r] + t1v[r];
        }
        rs += __shfl_xor(rs, 32);
        float al = exp2f(mo - mn);
        lrun = lrun * al + rs;
        mrun = mn;
        if (__any(mn != mo)) {
            #pragma unroll
            for (int dt = 0; dt < 8; dt++) o[dt] = o[dt] * al;
        }
        const char* Vs = smem + 65536 + (ch & 1) * 32768;
        #pragma unroll
        for (int pk = 0; pk < 4; pk++) {
            float e0 = (pk < 2) ? t0v[(pk & 1) * 8 + 0] : t1v[(pk & 1) * 8 + 0];
            float e1 = (pk < 2) ? t0v[(pk & 1) * 8 + 1] : t1v[(pk & 1) * 8 + 1];
            float e2 = (pk < 2) ? t0v[(pk & 1) * 8 + 2] : t1v[(pk & 1) * 8 + 2];
            float e3 = (pk < 2) ? t0v[(pk & 1) * 8 + 3] : t1v[(pk & 1) * 8 + 3];
            float e4 = (pk < 2) ? t0v[(pk & 1) * 8 + 4] : t1v[(pk & 1) * 8 + 4];
            float e5 = (pk < 2) ? t0v[(pk & 1) * 8 + 5] : t1v[(pk & 1) * 8 + 5];
            float e6 = (pk < 2) ? t0v[(pk & 1) * 8 + 6] : t1v[(pk & 1) * 8 + 6];
            float e7 = (pk < 2) ? t0v[(pk & 1) * 8 + 7] : t1v[(pk & 1) * 8 + 7];
            uint32_t A0 = pack2(e0, e1), A1 = pack2(e2, e3);
            uint32_t B0 = pack2(e4, e5), B1 = pack2(e6, e7);
            asm volatile("v_permlane32_swap_b32 %0, %1" : "+v"(B0), "+v"(A0));
            asm volatile("v_permlane32_swap_b32 %0, %1" : "+v"(B1), "+v"(A1));
            union { bf16x8 v; uint32_t u[4]; } pw;
            pw.u[0] = A0; pw.u[1] = A1; pw.u[2] = B0; pw.u[3] = B1;
            __builtin_amdgcn_s_setprio(1);
            #pragma unroll
            for (int dt = 0; dt < 8; dt++) {
                int d = dt * 32 + l31;
                int a = (d * 128 + pk * 32 + hi * 16) ^ (((d >> 2) & 31) << 4);
                bf16x8 vf = *(const bf16x8*)(Vs + a);
                o[dt] = MFMA32(vf, pw.v, o[dt]);
            }
            __builtin_amdgcn_s_setprio(0);
        }
    };

    // prologue
    stage_K(0); stage_V(0);
    WAITV8; SBAR;
    stage_K(1);
    qkt(0, sp0, sp1);
    WLG0; SBAR;
    stage_V(1);

    for (int ch = 1; ch < 16; ch++) {
        WAITV8; SBAR;
        if (ch < 15) stage_K(ch + 1);
        f32x16 sn0 = {}, sn1 = {};
        qkt(ch, sn0, sn1);
        smax_pv(sp0, sp1, ch - 1);
        WLG0; SBAR;
        if (ch < 15) stage_V(ch + 1);
        sp0 = sn0; sp1 = sn1;
    }
    WAITV0; SBAR;
    smax_pv(sp0, sp1, 15);

    float inv = 1.0f / lrun;
    char* aod = (char*)ao + (size_t)(b * 1024 + qg) * 512;
    #pragma unroll
    for (int dt = 0; dt < 8; dt++) {
        #pragma unroll
        for (int rg = 0; rg < 4; rg++) {
            bf16x4 w;
            #pragma unroll
            for (int r = 0; r < 4; r++) w[r] = (bf16_t)(o[dt][rg * 4 + r] * inv);
            *(bf16x4*)(aod + dt * 64 + rg * 16 + hi * 8) = w;
        }
    }
}

// ---------------- K4: out-proj GEMM + bias + residual (coalesced stores) ----------
// grid 256 token-tiles. A = wo (c rows, looped 4x dbuf), B = ao (tokens, staged once).
// D[c][tok]: lanes = tok -> coalesced fp32 stores + residual reads.
__global__ __launch_bounds__(256, 1) void gemm_out(const bf16_t* __restrict__ wo,
                                                   const bf16_t* __restrict__ ao,
                                                   const float* __restrict__ out_b,
                                                   const float* __restrict__ x,
                                                   float* __restrict__ out) {
    extern __shared__ char smem[];  // Bs(ao) 64KB | W dbuf 2x32KB
    char* Bs = smem;
    int tid = threadIdx.x, wv = tid >> 6, lane = tid & 63;
    int l31 = lane & 31, hi = lane >> 5;
    int t0 = blockIdx.x * 128;
    const char* bsrc = (const char*)ao + (size_t)t0 * 512;
    const char* wsrc = (const char*)wo;

    {
        int u = lane & 31, rofs = lane >> 5;
        #pragma unroll
        for (int t = 0; t < 16; t++) {
            int r0 = t * 8 + wv * 2;
            int r = r0 + rofs;
            GLL16(bsrc + (size_t)r * 512 + ((u ^ (r & 31)) * 16), Bs + r0 * 512);
        }
    }
    auto stage_W = [&](int ct) {
        char* Wd = smem + 65536 + (ct & 1) * 32768;
        int u = lane & 31, rofs = lane >> 5;
        #pragma unroll
        for (int t = 0; t < 8; t++) {
            int r0 = wv * 16 + t * 2;
            int r = r0 + rofs;
            GLL16(wsrc + (size_t)(ct * 64 + r) * 512 + ((u ^ (r & 31)) * 16), Wd + r0 * 512);
        }
    };
    stage_W(0);
    WAITV0; SBAR;

    int wm = wv >> 1, wc = wv & 1;
    int bb = t0 >> 10, pos0 = t0 & 1023;

    for (int ct = 0; ct < 4; ct++) {
        if (ct < 3) stage_W(ct + 1);
        const char* Ws = smem + 65536 + (ct & 1) * 32768;
        f32x16 acc0 = {}, acc1 = {};
        __builtin_amdgcn_s_setprio(1);
        #pragma unroll
        for (int ks = 0; ks < 16; ks++) {
            int col = ks * 32 + hi * 16;
            bf16x8 w  = *(const bf16x8*)(Ws + (wc * 32 + l31) * 512 + (col ^ (l31 << 4)));
            bf16x8 b0 = *(const bf16x8*)(Bs + (wm * 64 + l31) * 512 + (col ^ (l31 << 4)));
            bf16x8 b1 = *(const bf16x8*)(Bs + (wm * 64 + 32 + l31) * 512 + (col ^ (l31 << 4)));
            acc0 = MFMA32(w, b0, acc0);
            acc1 = MFMA32(w, b1, acc1);
        }
        __builtin_amdgcn_s_setprio(0);
        #pragma unroll
        for (int ms = 0; ms < 2; ms++) {
            int pos = pos0 + wm * 64 + ms * 32 + l31;
            #pragma unroll
            for (int r = 0; r < 16; r++) {
                float v = ms ? acc1[r] : acc0[r];
                int c = ct * 64 + wc * 32 + (r & 3) + 8 * (r >> 2) + 4 * hi;
                size_t idx = ((size_t)bb * 256 + c) * 1024 + pos;
                out[idx] = v + out_b[c] + x[idx];
            }
        }
        if (ct < 3) { WAITV0; SBAR; }
    }
}

// ---------------- launcher ----------------
extern "C" void kernel_launch(void* const* d_in, const int* in_sizes, int n_in,
                              void* d_out, int out_size, void* d_ws, size_t ws_size,
                              hipStream_t stream) {
    (void)in_sizes; (void)n_in; (void)out_size; (void)ws_size;
    const float* x      = (const float*)d_in[0];
    const float* gamma  = (const float*)d_in[1];
    const float* beta   = (const float*)d_in[2];
    const float* qkv_w  = (const float*)d_in[3];
    const float* qkv_b  = (const float*)d_in[4];
    const float* out_w  = (const float*)d_in[5];
    const float* out_b  = (const float*)d_in[6];
    float* out = (float*)d_out;

    char* ws = (char*)d_ws;
    const size_t MB16 = 16777216;
    bf16_t* xn  = (bf16_t*)(ws);             // (b, n, 256) bf16
    bf16_t* qb  = (bf16_t*)(ws + 1 * MB16);  // (b, n, 256)  pre-scaled by QSCALE
    bf16_t* kb  = (bf16_t*)(ws + 2 * MB16);  // (b, n, 256)
    bf16_t* vt  = (bf16_t*)(ws + 3 * MB16);  // (b, 256, n)  V transposed
    bf16_t* ao  = (bf16_t*)(ws + 4 * MB16);  // (b, n, 256)
    bf16_t* wqb = (bf16_t*)(ws + 5 * MB16);            // 768x256 bf16
    bf16_t* wob = (bf16_t*)(ws + 5 * MB16 + 393216);   // 256x256 bf16

    cast_w<<<256, 256, 0, stream>>>(qkv_w, wqb, 196608, out_w, wob, 65536);
    gn_kernel<<<256, 256, 65600, stream>>>(x, gamma, beta, xn);
    gemm_qkv<<<256, 256, 131072, stream>>>(xn, wqb, qkv_b, qb, kb, vt);
    attn_kernel<<<256, 256, 131072, stream>>>(qb, kb, vt, ao);
    gemm_out<<<256, 256, 131072, stream>>>(wob, ao, out_b, x, out);
}